// Round 6
// baseline (16.765 us; speedup 1.0000x reference)
//
#include <hip/hip_runtime.h>
#include <math.h>

#define EPS 1e-8f
#define D 128
#define K 5
#define NG 16          // level-1 groups
#define CPAD 16        // counter padding: 16 u32 = 64B apart

// Single-dispatch fused loss, last-block reduction via hierarchical tickets.
// 256 blocks x 256 threads; 16 lanes per row (16 rows/block).
// Each block: one float partial (agent-scope store) + ONE release fetch_add
// on its group counter (16 adds/counter -> no same-address pileup, R3 lesson).
// Group winners (old+1 % 16 == 0) take one add on the level-2 counter; the
// global winner's block reduces all 256 partials in index order (bit-stable
// regardless of which block wins) and writes out[0]. No polling (R4 lesson).
// Counters are never reset: each replay adds exactly 16 per counter, and a
// window of 16 consecutive values contains exactly one == -1 mod 16, for any
// poison start (2^32 % 16 == 0 so wrap is harmless).
__global__ __launch_bounds__(256) void simloss_onepass(
    const float* __restrict__ ue,      // [B, D]
    const float* __restrict__ se,      // [B, D]
    const float* __restrict__ tu,      // [NU, D]
    const float* __restrict__ ts,      // [NS, D]
    const int*   __restrict__ busers,  // [B]
    const int*   __restrict__ negidx,  // [B, K]
    float*       __restrict__ out,     // [1]
    float*       __restrict__ partials,// [nblk]
    unsigned*    __restrict__ cnt1,    // [NG * CPAD], stride CPAD
    unsigned*    __restrict__ cnt2,    // [1]
    int B, float invB, int nblk)
{
    const int bid = blockIdx.x;
    const int t   = threadIdx.x;
    const int tid = bid * 256 + t;
    const int row = tid >> 4;          // one row per 16 lanes
    const int r   = t & 15;

    float diff = 0.0f;                 // neg_mean - pos
    if (row < B) {
        const int uidx = busers[row];
        int nidx[K];
        #pragma unroll
        for (int k = 0; k < K; ++k) nidx[k] = negidx[row * K + k];

        const float4* A  = (const float4*)(ue + (size_t)row * D);
        const float4* Bv = (const float4*)(se + (size_t)row * D);
        const float4 a0 = A[r],  a1 = A[r + 16];
        const float4 b0 = Bv[r], b1 = Bv[r + 16];
        float dot = a0.x*b0.x + a0.y*b0.y + a0.z*b0.z + a0.w*b0.w
                  + a1.x*b1.x + a1.y*b1.y + a1.z*b1.z + a1.w*b1.w;
        float na  = a0.x*a0.x + a0.y*a0.y + a0.z*a0.z + a0.w*a0.w
                  + a1.x*a1.x + a1.y*a1.y + a1.z*a1.z + a1.w*a1.w;
        float nb  = b0.x*b0.x + b0.y*b0.y + b0.z*b0.z + b0.w*b0.w
                  + b1.x*b1.x + b1.y*b1.y + b1.z*b1.z + b1.w*b1.w;

        const float4* Cv = (const float4*)(tu + (size_t)uidx * D);
        const float4 c0 = Cv[r], c1 = Cv[r + 16];
        float nc = c0.x*c0.x + c0.y*c0.y + c0.z*c0.z + c0.w*c0.w
                 + c1.x*c1.x + c1.y*c1.y + c1.z*c1.z + c1.w*c1.w;

        float dk[K], nk[K];
        #pragma unroll
        for (int k = 0; k < K; ++k) {
            const float4* E = (const float4*)(ts + (size_t)nidx[k] * D);
            const float4 e0 = E[r], e1 = E[r + 16];
            dk[k] = c0.x*e0.x + c0.y*e0.y + c0.z*e0.z + c0.w*e0.w
                  + c1.x*e1.x + c1.y*e1.y + c1.z*e1.z + c1.w*e1.w;
            nk[k] = e0.x*e0.x + e0.y*e0.y + e0.z*e0.z + e0.w*e0.w
                  + e1.x*e1.x + e1.y*e1.y + e1.z*e1.z + e1.w*e1.w;
        }

        #pragma unroll
        for (int off = 8; off > 0; off >>= 1) {
            dot += __shfl_xor(dot, off);
            na  += __shfl_xor(na,  off);
            nb  += __shfl_xor(nb,  off);
            nc  += __shfl_xor(nc,  off);
            #pragma unroll
            for (int k = 0; k < K; ++k) {
                dk[k] += __shfl_xor(dk[k], off);
                nk[k] += __shfl_xor(nk[k], off);
            }
        }

        const float pos = dot * rsqrtf(fmaxf(na, EPS * EPS))
                              * rsqrtf(fmaxf(nb, EPS * EPS));
        const float rc  = rsqrtf(fmaxf(nc, EPS * EPS));
        float s = 0.0f;
        #pragma unroll
        for (int k = 0; k < K; ++k)
            s += dk[k] * rc * rsqrtf(fmaxf(nk[k], EPS * EPS));
        diff = s * (1.0f / K) - pos;
    }

    __shared__ float sp[16];
    __shared__ int win;
    if (r == 0) sp[t >> 4] = diff;
    __syncthreads();

    if (t == 0) {
        float bp = 0.0f;
        #pragma unroll
        for (int i = 0; i < 16; ++i) bp += sp[i];
        // publish partial at the coherent point (agent scope)
        __hip_atomic_store((unsigned*)&partials[bid],
                           __builtin_bit_cast(unsigned, bp),
                           __ATOMIC_RELAXED, __HIP_MEMORY_SCOPE_AGENT);
        __threadfence();
        const int g = bid & (NG - 1);   // 16 blocks per group
        int w2 = 0;
        const unsigned o1 = __hip_atomic_fetch_add(&cnt1[g * CPAD], 1u,
                               __ATOMIC_ACQ_REL, __HIP_MEMORY_SCOPE_AGENT);
        if (((o1 + 1u) & (unsigned)(nblk / NG - 1)) == 0u) {   // group winner
            const unsigned o2 = __hip_atomic_fetch_add(cnt2, 1u,
                                   __ATOMIC_ACQ_REL, __HIP_MEMORY_SCOPE_AGENT);
            w2 = (((o2 + 1u) & (NG - 1)) == 0u);               // global winner
        }
        win = w2;
    }
    __syncthreads();
    if (!win) return;

    // ---- global winner: reduce all partials (fixed index order) ----
    __threadfence();
    float s = 0.0f;
    if (t < nblk) {
        const unsigned u = __hip_atomic_load((unsigned*)&partials[t],
                              __ATOMIC_RELAXED, __HIP_MEMORY_SCOPE_AGENT);
        s = __builtin_bit_cast(float, u);
    }
    #pragma unroll
    for (int off = 32; off > 0; off >>= 1) s += __shfl_xor(s, off);

    __shared__ float lw[4];
    const int lane = t & 63, wave = t >> 6;
    if (lane == 0) lw[wave] = s;
    __syncthreads();
    if (t == 0)
        out[0] = 1.0f + (lw[0] + lw[1] + lw[2] + lw[3]) * invB;
}

// Fallback 2-dispatch final stage (only used if nblk != 256).
__global__ __launch_bounds__(256) void simloss_final(
    const float* __restrict__ partials, float* __restrict__ out,
    int nblk, float invB)
{
    const int t = threadIdx.x;
    float s = 0.0f;
    for (int i = t; i < nblk; i += 256) s += partials[i];
    #pragma unroll
    for (int off = 32; off > 0; off >>= 1) s += __shfl_xor(s, off);
    __shared__ float lw[4];
    const int lane = t & 63, wave = t >> 6;
    if (lane == 0) lw[wave] = s;
    __syncthreads();
    if (t == 0) out[0] = 1.0f + (lw[0] + lw[1] + lw[2] + lw[3]) * invB;
}

extern "C" void kernel_launch(void* const* d_in, const int* in_sizes, int n_in,
                              void* d_out, int out_size, void* d_ws, size_t ws_size,
                              hipStream_t stream) {
    const float* ue = (const float*)d_in[0];
    const float* se = (const float*)d_in[1];
    const float* tu = (const float*)d_in[2];
    const float* ts = (const float*)d_in[3];
    const int*   bu = (const int*)d_in[4];
    const int*   ni = (const int*)d_in[5];
    float* out = (float*)d_out;

    const int B = in_sizes[0] / D;               // 4096
    const int nblk = (B * 16 + 255) / 256;       // 256 blocks, 16 rows each

    float*    partials = (float*)d_ws;                    // nblk floats
    unsigned* cnt1     = (unsigned*)(partials + nblk);    // NG*CPAD u32
    unsigned* cnt2     = cnt1 + NG * CPAD;                // 1 u32

    if (nblk == 256) {
        simloss_onepass<<<nblk, 256, 0, stream>>>(ue, se, tu, ts, bu, ni, out,
                                                  partials, cnt1, cnt2,
                                                  B, 1.0f / (float)B, nblk);
    } else {
        // generic path: keep correctness for unexpected shapes
        simloss_onepass<<<nblk, 256, 0, stream>>>(ue, se, tu, ts, bu, ni, out,
                                                  partials, cnt1, cnt2,
                                                  B, 1.0f / (float)B, nblk);
        simloss_final<<<1, 256, 0, stream>>>(partials, out, nblk, 1.0f / (float)B);
    }
}